// Round 4
// baseline (362.125 us; speedup 1.0000x reference)
//
#include <hip/hip_runtime.h>
#include <hip/hip_bf16.h>

#define NSTEPS 5

typedef __attribute__((ext_vector_type(8))) short short8;
typedef __attribute__((ext_vector_type(4))) float floatx4;

static __device__ __forceinline__ unsigned pk2bf(float a, float b) {
    __hip_bfloat162 h = __float22bfloat162_rn(make_float2(a, b));
    return *reinterpret_cast<unsigned*>(&h);
}

struct Params {
    const float *J, *b, *W1, *b1, *W2, *b2, *W3, *b3;
    const float *W_ih, *b_ih, *W_hh, *b_hh;
    const float *Wr1, *br1, *Wr2, *br2, *Wr3, *br3;
    float *out;
    float *aA, *aB;        // double-buffered a-projection (512x64 each)
    unsigned *bar;         // [count, generation]
};

// Grid barrier. Safe: grid=256 blocks, max occupancy >=2 blocks/CU on 256 CUs,
// so all blocks are resident under any placement -> no deadlock possible.
static __device__ __forceinline__ void gbar(unsigned* bar, unsigned target) {
    __threadfence();                       // release: push this block's global stores
    __syncthreads();
    if (threadIdx.x == 0) {
        unsigned old = __hip_atomic_fetch_add(&bar[0], 1u, __ATOMIC_ACQ_REL,
                                              __HIP_MEMORY_SCOPE_AGENT);
        if (old == 255u) {
            __hip_atomic_store(&bar[0], 0u, __ATOMIC_RELAXED, __HIP_MEMORY_SCOPE_AGENT);
            __hip_atomic_fetch_add(&bar[1], 1u, __ATOMIC_RELEASE, __HIP_MEMORY_SCOPE_AGENT);
        } else {
            while (__hip_atomic_load(&bar[1], __ATOMIC_ACQUIRE,
                                     __HIP_MEMORY_SCOPE_AGENT) < target) {
                __builtin_amdgcn_s_sleep(1);
            }
        }
    }
    __syncthreads();
    __threadfence();                       // acquire: invalidate stale cached lines
}

__global__ __launch_bounds__(256, 2) void ggnn_fused(Params p)
{
    const int tid = threadIdx.x;
    const int l = tid & 63, w = tid >> 6;
    const int m = l & 15, q = l >> 4;
    const int j0 = blockIdx.x, j1 = blockIdx.x + 256;

    __shared__ __align__(16) float smJ[2][512];
    __shared__ __align__(16) float smW1hi[64][16];
    __shared__ __align__(16) float smW1hj[64][16];
    __shared__ __align__(16) float smwJ[64], smwbi[64], smwbj[64], smb1[64];
    __shared__ __align__(16) float smC[2][64];
    __shared__ __align__(16) float smH[2][16];
    __shared__ __align__(16) float smWave[2][4][64];
    __shared__ __align__(16) float smMacc[2][64];
    __shared__ __align__(16) float smGin[2][48];   // [h(16), msg(32)]
    __shared__ __align__(16) float smGi[2][48];
    __shared__ __align__(16) float smGh[2][48];
    __shared__ __align__(16) float smY[2][64];
    __shared__ __align__(16) float smY2[2][64];
    __shared__ float smR[2][2];

    // ---- init: gather 2 J-columns, stage W1 pieces, pack W2 frags in regs ----
    #pragma unroll
    for (int r = 0; r < 2; ++r) {
        int i = r * 256 + tid;
        smJ[0][i] = p.J[i * 512 + j0];
        smJ[1][i] = p.J[i * 512 + j1];
    }
    if (tid < 64) {
        int o = tid;
        #pragma unroll
        for (int s = 0; s < 16; ++s) {
            smW1hi[o][s] = p.W1[o * 35 + s];
            smW1hj[o][s] = p.W1[o * 35 + 16 + s];
        }
        smwJ[o]  = p.W1[o * 35 + 32];
        smwbi[o] = p.W1[o * 35 + 33];
        smwbj[o] = p.W1[o * 35 + 34];
        smb1[o]  = p.b1[o];
    }

    short8 bfw[4][2];
    float b2n[4];
    {
        const floatx4* W2v = (const floatx4*)p.W2;
        #pragma unroll
        for (int nt = 0; nt < 4; ++nt) {
            int n = nt * 16 + m;
            #pragma unroll
            for (int ks = 0; ks < 2; ++ks) {
                int kb = ks * 32 + q * 8;
                floatx4 f0 = W2v[n * 16 + (kb >> 2)];
                floatx4 f1 = W2v[n * 16 + (kb >> 2) + 1];
                union { short8 s; unsigned u[4]; } t;
                t.u[0] = pk2bf(f0[0], f0[1]); t.u[1] = pk2bf(f0[2], f0[3]);
                t.u[2] = pk2bf(f1[0], f1[1]); t.u[3] = pk2bf(f1[2], f1[3]);
                bfw[nt][ks] = t.s;
            }
            b2n[nt] = p.b2[nt * 16 + m];
        }
    }
    __syncthreads();

    float bj[2] = { p.b[j0], p.b[j1] };

    floatx4 wva, wvb, wvc, wvd;
    {
        const floatx4* wv4 = (const floatx4*)smwJ;
        wva = wv4[q * 2];     wvb = wv4[q * 2 + 1];
        wvc = wv4[8 + q * 2]; wvd = wv4[8 + q * 2 + 1];
    }

    if (tid < 128) {                       // a0 rows + c0 for both owned columns
        int col = tid >> 6, o = tid & 63;
        int jc = col ? j1 : j0;
        p.aA[jc * 64 + o] = bj[col] * smwbi[o];            // h0 = 0
        smC[col][o] = bj[col] * smwbj[o] + smb1[o];
    }
    if (tid < 32) smH[tid >> 4][tid & 15] = 0.f;

    gbar(p.bar, 1);                        // a0 visible grid-wide

    const float* aIn = p.aA;
    float* aOut = p.aB;

    for (int t = 0; t < NSTEPS; ++t) {
        const floatx4* c40 = (const floatx4*)&smC[0][0];
        const floatx4* c41 = (const floatx4*)&smC[1][0];
        floatx4 cva0 = c40[q*2], cvb0 = c40[q*2+1], cvc0 = c40[8+q*2], cvd0 = c40[8+q*2+1];
        floatx4 cva1 = c41[q*2], cvb1 = c41[q*2+1], cvc1 = c41[8+q*2], cvd1 = c41[8+q*2+1];

        floatx4 acc[2][4];
        #pragma unroll
        for (int col = 0; col < 2; ++col)
            #pragma unroll
            for (int nt = 0; nt < 4; ++nt) acc[col][nt] = (floatx4){0.f,0.f,0.f,0.f};

        const floatx4* a4 = (const floatx4*)aIn;

        for (int c8 = 0; c8 < 8; ++c8) {
            int i = w * 128 + c8 * 16 + m;
            float J0 = smJ[0][i], J1 = smJ[1][i];
            floatx4 av0 = a4[i*16 + q*2],     av1 = a4[i*16 + q*2 + 1];
            floatx4 av2 = a4[i*16 + 8 + q*2], av3 = a4[i*16 + 8 + q*2 + 1];

            floatx4 x0, x1, x2, x3;
            union { short8 s; unsigned u[4]; } fa0, fa1, fb0, fb1;
            #pragma unroll
            for (int e = 0; e < 4; ++e) {
                x0[e] = fmaxf(fmaf(J0, wva[e], av0[e]) + cva0[e], 0.f);
                x1[e] = fmaxf(fmaf(J0, wvb[e], av1[e]) + cvb0[e], 0.f);
                x2[e] = fmaxf(fmaf(J0, wvc[e], av2[e]) + cvc0[e], 0.f);
                x3[e] = fmaxf(fmaf(J0, wvd[e], av3[e]) + cvd0[e], 0.f);
            }
            fa0.u[0] = pk2bf(x0[0], x0[1]); fa0.u[1] = pk2bf(x0[2], x0[3]);
            fa0.u[2] = pk2bf(x1[0], x1[1]); fa0.u[3] = pk2bf(x1[2], x1[3]);
            fa1.u[0] = pk2bf(x2[0], x2[1]); fa1.u[1] = pk2bf(x2[2], x2[3]);
            fa1.u[2] = pk2bf(x3[0], x3[1]); fa1.u[3] = pk2bf(x3[2], x3[3]);
            #pragma unroll
            for (int e = 0; e < 4; ++e) {
                x0[e] = fmaxf(fmaf(J1, wva[e], av0[e]) + cva1[e], 0.f);
                x1[e] = fmaxf(fmaf(J1, wvb[e], av1[e]) + cvb1[e], 0.f);
                x2[e] = fmaxf(fmaf(J1, wvc[e], av2[e]) + cvc1[e], 0.f);
                x3[e] = fmaxf(fmaf(J1, wvd[e], av3[e]) + cvd1[e], 0.f);
            }
            fb0.u[0] = pk2bf(x0[0], x0[1]); fb0.u[1] = pk2bf(x0[2], x0[3]);
            fb0.u[2] = pk2bf(x1[0], x1[1]); fb0.u[3] = pk2bf(x1[2], x1[3]);
            fb1.u[0] = pk2bf(x2[0], x2[1]); fb1.u[1] = pk2bf(x2[2], x2[3]);
            fb1.u[2] = pk2bf(x3[0], x3[1]); fb1.u[3] = pk2bf(x3[2], x3[3]);

            #pragma unroll
            for (int nt = 0; nt < 4; ++nt) {
                floatx4 d = {0.f,0.f,0.f,0.f};
                d = __builtin_amdgcn_mfma_f32_16x16x32_bf16(fa0.s, bfw[nt][0], d, 0, 0, 0);
                d = __builtin_amdgcn_mfma_f32_16x16x32_bf16(fa1.s, bfw[nt][1], d, 0, 0, 0);
                floatx4 d2 = {0.f,0.f,0.f,0.f};
                d2 = __builtin_amdgcn_mfma_f32_16x16x32_bf16(fb0.s, bfw[nt][0], d2, 0, 0, 0);
                d2 = __builtin_amdgcn_mfma_f32_16x16x32_bf16(fb1.s, bfw[nt][1], d2, 0, 0, 0);
                #pragma unroll
                for (int r = 0; r < 4; ++r) {
                    acc[0][nt][r] += fmaxf(d[r]  + b2n[nt], 0.f);
                    acc[1][nt][r] += fmaxf(d2[r] + b2n[nt], 0.f);
                }
            }
        }

        // per-col reduction over i
        #pragma unroll
        for (int col = 0; col < 2; ++col)
            #pragma unroll
            for (int nt = 0; nt < 4; ++nt) {
                float v = acc[col][nt][0] + acc[col][nt][1] + acc[col][nt][2] + acc[col][nt][3];
                v += __shfl_xor(v, 16);
                v += __shfl_xor(v, 32);
                if (l < 16) smWave[col][w][nt*16 + l] = v;
            }
        if (tid < 32) smGin[tid >> 4][tid & 15] = smH[tid >> 4][tid & 15];
        __syncthreads();
        if (tid < 128) {
            int col = tid >> 6, o = tid & 63;
            smMacc[col][o] = smWave[col][0][o] + smWave[col][1][o]
                           + smWave[col][2][o] + smWave[col][3][o];
        }
        __syncthreads();

        // msg = W3 @ macc + 512*b3 (per col: 32 outs x 4 partials)
        {
            int col = tid >> 7, t2 = tid & 127;
            int o = t2 >> 2, pp = t2 & 3;
            const floatx4* W3v = (const floatx4*)p.W3;
            floatx4 w0 = W3v[o*16 + pp*4],     w1 = W3v[o*16 + pp*4 + 1];
            floatx4 w2 = W3v[o*16 + pp*4 + 2], w3 = W3v[o*16 + pp*4 + 3];
            float part = 0.f;
            #pragma unroll
            for (int e = 0; e < 4; ++e) {
                part = fmaf(w0[e], smMacc[col][pp*16 + e],      part);
                part = fmaf(w1[e], smMacc[col][pp*16 + 4 + e],  part);
                part = fmaf(w2[e], smMacc[col][pp*16 + 8 + e],  part);
                part = fmaf(w3[e], smMacc[col][pp*16 + 12 + e], part);
            }
            part += __shfl_xor(part, 1);
            part += __shfl_xor(part, 2);
            if (pp == 0) smGin[col][16 + o] = part + 512.f * p.b3[o];
        }
        __syncthreads();

        // GRU gates: per col, t2<48 -> gi (serial 48-dot), t2 in [64,112) -> gh
        {
            int col = tid >> 7, t2 = tid & 127;
            if (t2 < 48) {
                const floatx4* Wv = (const floatx4*)p.W_ih;
                const floatx4* g4 = (const floatx4*)&smGin[col][0];
                float s = p.b_ih[t2];
                #pragma unroll
                for (int e = 0; e < 12; ++e) {
                    floatx4 we = Wv[t2*12 + e], ge = g4[e];
                    s = fmaf(we[0], ge[0], s); s = fmaf(we[1], ge[1], s);
                    s = fmaf(we[2], ge[2], s); s = fmaf(we[3], ge[3], s);
                }
                smGi[col][t2] = s;
            } else if (t2 >= 64 && t2 < 112) {
                int o = t2 - 64;
                const floatx4* Wv = (const floatx4*)p.W_hh;
                const floatx4* h4 = (const floatx4*)&smGin[col][0];  // old h
                float s = p.b_hh[o];
                #pragma unroll
                for (int e = 0; e < 4; ++e) {
                    floatx4 we = Wv[o*4 + e], he = h4[e];
                    s = fmaf(we[0], he[0], s); s = fmaf(we[1], he[1], s);
                    s = fmaf(we[2], he[2], s); s = fmaf(we[3], he[3], s);
                }
                smGh[col][o] = s;
            }
        }
        __syncthreads();

        if (tid < 32) {
            int col = tid >> 4, o = tid & 15;
            float r = 1.f / (1.f + __expf(-(smGi[col][o] + smGh[col][o])));
            float z = 1.f / (1.f + __expf(-(smGi[col][16+o] + smGh[col][16+o])));
            float n = tanhf(smGi[col][32+o] + r * smGh[col][32+o]);
            smH[col][o] = (1.f - z) * n + z * smGin[col][o];
        }
        __syncthreads();

        if (t < NSTEPS - 1) {
            // next projections: per col 128 threads (64 a -> global, 64 c -> LDS)
            {
                int col = tid >> 7, t2 = tid & 127, o = t2 & 63, sel = t2 >> 6;
                const floatx4* Wv = (const floatx4*)(sel ? &smW1hj[0][0] : &smW1hi[0][0]);
                const floatx4* h4 = (const floatx4*)&smH[col][0];
                floatx4 w0 = Wv[o*4], w1 = Wv[o*4+1], w2 = Wv[o*4+2], w3 = Wv[o*4+3];
                float s = 0.f;
                #pragma unroll
                for (int e = 0; e < 4; ++e) {
                    s = fmaf(w0[e], h4[0][e], s);
                    s = fmaf(w1[e], h4[1][e], s);
                    s = fmaf(w2[e], h4[2][e], s);
                    s = fmaf(w3[e], h4[3][e], s);
                }
                int jc = col ? j1 : j0;
                if (sel == 0) aOut[jc*64 + o] = s + bj[col] * smwbi[o];
                else          smC[col][o]     = s + bj[col] * smwbj[o] + smb1[o];
            }
            gbar(p.bar, (unsigned)(t + 2));
            const float* tmp = aIn; aIn = aOut; aOut = (float*)tmp;
        }
    }

    // ---- fused readout for both owned nodes ----
    {
        int col = tid >> 7, t2 = tid & 127;
        if (t2 < 64) {
            const floatx4* Wv = (const floatx4*)p.Wr1;
            const floatx4* h4 = (const floatx4*)&smH[col][0];
            floatx4 w0 = Wv[t2*4], w1 = Wv[t2*4+1], w2 = Wv[t2*4+2], w3 = Wv[t2*4+3];
            float s = p.br1[t2];
            #pragma unroll
            for (int e = 0; e < 4; ++e) {
                s = fmaf(w0[e], h4[0][e], s);
                s = fmaf(w1[e], h4[1][e], s);
                s = fmaf(w2[e], h4[2][e], s);
                s = fmaf(w3[e], h4[3][e], s);
            }
            smY[col][t2] = fmaxf(s, 0.f);
        }
    }
    __syncthreads();
    {
        int col = tid >> 7, t2 = tid & 127;
        int o = t2 >> 1, pp = t2 & 1;
        const floatx4* Wv = (const floatx4*)p.Wr2;
        const floatx4* y4 = (const floatx4*)&smY[col][0];
        float part = 0.f;
        #pragma unroll
        for (int e = 0; e < 8; ++e) {
            floatx4 we = Wv[o*16 + pp*8 + e], ye = y4[pp*8 + e];
            part = fmaf(we[0], ye[0], part); part = fmaf(we[1], ye[1], part);
            part = fmaf(we[2], ye[2], part); part = fmaf(we[3], ye[3], part);
        }
        part += __shfl_xor(part, 1);
        if (pp == 0) smY2[col][o] = fmaxf(part + p.br2[o], 0.f);
    }
    __syncthreads();
    {
        int col = tid >> 7, t2 = tid & 127;
        int ot = t2 >> 6, pp = t2 & 63;
        float part = p.Wr3[ot*64 + pp] * smY2[col][pp];
        part += __shfl_xor(part, 1);
        part += __shfl_xor(part, 2);
        part += __shfl_xor(part, 4);
        part += __shfl_xor(part, 8);
        part += __shfl_xor(part, 16);
        part += __shfl_xor(part, 32);
        if (pp == 0) smR[col][ot] = part + p.br3[ot];
    }
    __syncthreads();
    if (tid < 2) {
        int col = tid;
        int jc = col ? j1 : j0;
        float e0 = 1.f / (1.f + __expf(-smR[col][0]));
        float e1 = 1.f / (1.f + __expf(-smR[col][1]));
        float tsum = e0 + e1;
        p.out[jc*2]     = e0 / tsum;
        p.out[jc*2 + 1] = e1 / tsum;
    }
}

extern "C" void kernel_launch(void* const* d_in, const int* in_sizes, int n_in,
                              void* d_out, int out_size, void* d_ws, size_t ws_size,
                              hipStream_t stream)
{
    Params par;
    par.J    = (const float*)d_in[0];
    par.b    = (const float*)d_in[1];
    par.W1   = (const float*)d_in[2];
    par.b1   = (const float*)d_in[3];
    par.W2   = (const float*)d_in[4];
    par.b2   = (const float*)d_in[5];
    par.W3   = (const float*)d_in[6];
    par.b3   = (const float*)d_in[7];
    par.W_ih = (const float*)d_in[8];
    par.b_ih = (const float*)d_in[9];
    par.W_hh = (const float*)d_in[10];
    par.b_hh = (const float*)d_in[11];
    par.Wr1  = (const float*)d_in[12];
    par.br1  = (const float*)d_in[13];
    par.Wr2  = (const float*)d_in[14];
    par.br2  = (const float*)d_in[15];
    par.Wr3  = (const float*)d_in[16];
    par.br3  = (const float*)d_in[17];
    par.out  = (float*)d_out;

    float* ws = (float*)d_ws;
    par.aA  = ws;                          // 512*64 floats
    par.aB  = ws + 512 * 64;               // 512*64 floats
    par.bar = (unsigned*)(ws + 2 * 512 * 64);

    hipMemsetAsync(par.bar, 0, 64, stream);     // barrier state (ws is poisoned 0xAA)
    hipLaunchKernelGGL(ggnn_fused, dim3(256), dim3(256), 0, stream, par);
}

// Round 5
// 300.691 us; speedup vs baseline: 1.2043x; 1.2043x over previous
//
#include <hip/hip_runtime.h>
#include <hip/hip_bf16.h>

#define NSTEPS 5

typedef __attribute__((ext_vector_type(8))) short short8;
typedef __attribute__((ext_vector_type(4))) float floatx4;

static __device__ __forceinline__ unsigned pk2bf(float a, float b) {
    __hip_bfloat162 h = __float22bfloat162_rn(make_float2(a, b));
    return *reinterpret_cast<unsigned*>(&h);
}

struct Params {
    const float *J, *b, *W1, *b1, *W2, *b2, *W3, *b3;
    const float *W_ih, *b_ih, *W_hh, *b_hh;
    const float *Wr1, *br1, *Wr2, *br2, *Wr3, *br3;
    float *out;
    float *aA, *aB;        // double-buffered a-projection (512x64 each)
    float *Jt;             // transposed J (512x512)
    unsigned *bar;         // tree barrier state (monotonic counters)
};

// Monotonic tree grid barrier, 256 blocks. All atomics RELAXED (no per-poll
// L2 invalidates); data visibility via the two __threadfence() (release before
// arrival: wbl2 pushes this block's stores to L3; acquire after exit: inv).
// Counters never reset -> no reset/arrival races. bar layout (64B-line spaced):
// bar[g*16] g=0..7 group counters, bar[128] master, bar[144] generation.
static __device__ __forceinline__ void gbar(unsigned* bar, unsigned ph) {
    __threadfence();                       // release: drain + writeback L2
    __syncthreads();
    if (threadIdx.x == 0) {
        const int g = blockIdx.x & 7;
        unsigned old = __hip_atomic_fetch_add(&bar[g * 16], 1u, __ATOMIC_RELAXED,
                                              __HIP_MEMORY_SCOPE_AGENT);
        if (old == 32u * ph - 1u) {        // last of this group for phase ph
            unsigned mo = __hip_atomic_fetch_add(&bar[128], 1u, __ATOMIC_RELAXED,
                                                 __HIP_MEMORY_SCOPE_AGENT);
            if (mo == 8u * ph - 1u)        // last group -> publish generation
                __hip_atomic_store(&bar[144], ph, __ATOMIC_RELAXED,
                                   __HIP_MEMORY_SCOPE_AGENT);
        }
        while (__hip_atomic_load(&bar[144], __ATOMIC_RELAXED,
                                 __HIP_MEMORY_SCOPE_AGENT) < ph)
            __builtin_amdgcn_s_sleep(2);
    }
    __syncthreads();
    __threadfence();                       // acquire: invalidate stale lines
}

__global__ __launch_bounds__(256, 2) void ggnn_fused(Params p)
{
    const int tid = threadIdx.x;
    const int l = tid & 63, w = tid >> 6;
    const int m = l & 15, q = l >> 4;
    const int j0 = blockIdx.x, j1 = blockIdx.x + 256;

    __shared__ __align__(16) float smTile[64][65];   // transpose staging
    __shared__ __align__(16) float smJ[2][512];
    __shared__ __align__(16) float smW1hi[64][16];
    __shared__ __align__(16) float smW1hj[64][16];
    __shared__ __align__(16) float smwJ[64], smwbi[64], smwbj[64], smb1[64];
    __shared__ __align__(16) float smC[2][64];
    __shared__ __align__(16) float smH[2][16];
    __shared__ __align__(16) float smWave[2][4][64];
    __shared__ __align__(16) float smMacc[2][64];
    __shared__ __align__(16) float smGin[2][48];   // [h(16), msg(32)]
    __shared__ __align__(16) float smGi[2][48];
    __shared__ __align__(16) float smGh[2][48];
    __shared__ __align__(16) float smY[2][64];
    __shared__ __align__(16) float smY2[2][64];
    __shared__ float smR[2][2];

    // ---- phase 0a: blocks 0..63 transpose J into Jt (coalesced both ways) ----
    if (blockIdx.x < 64) {
        int ti = blockIdx.x >> 3, tj = blockIdx.x & 7;
        for (int pp = 0; pp < 16; ++pp) {
            int e = pp * 256 + tid; int r = e >> 6, c = e & 63;
            smTile[r][c] = p.J[(ti * 64 + r) * 512 + tj * 64 + c];
        }
        __syncthreads();
        for (int pp = 0; pp < 16; ++pp) {
            int e = pp * 256 + tid; int r = e >> 6, c = e & 63;
            p.Jt[(tj * 64 + r) * 512 + ti * 64 + c] = smTile[c][r];
        }
    }

    // ---- phase 0b: stage weights, pack W2 frags, a0/c0 ----
    if (tid < 64) {
        int o = tid;
        #pragma unroll
        for (int s = 0; s < 16; ++s) {
            smW1hi[o][s] = p.W1[o * 35 + s];
            smW1hj[o][s] = p.W1[o * 35 + 16 + s];
        }
        smwJ[o]  = p.W1[o * 35 + 32];
        smwbi[o] = p.W1[o * 35 + 33];
        smwbj[o] = p.W1[o * 35 + 34];
        smb1[o]  = p.b1[o];
    }

    short8 bfw[4][2];
    float b2n[4];
    {
        const floatx4* W2v = (const floatx4*)p.W2;
        #pragma unroll
        for (int nt = 0; nt < 4; ++nt) {
            int n = nt * 16 + m;
            #pragma unroll
            for (int ks = 0; ks < 2; ++ks) {
                int kb = ks * 32 + q * 8;
                floatx4 f0 = W2v[n * 16 + (kb >> 2)];
                floatx4 f1 = W2v[n * 16 + (kb >> 2) + 1];
                union { short8 s; unsigned u[4]; } t;
                t.u[0] = pk2bf(f0[0], f0[1]); t.u[1] = pk2bf(f0[2], f0[3]);
                t.u[2] = pk2bf(f1[0], f1[1]); t.u[3] = pk2bf(f1[2], f1[3]);
                bfw[nt][ks] = t.s;
            }
            b2n[nt] = p.b2[nt * 16 + m];
        }
    }
    __syncthreads();

    float bj[2] = { p.b[j0], p.b[j1] };

    floatx4 wva, wvb, wvc, wvd;
    {
        const floatx4* wv4 = (const floatx4*)smwJ;
        wva = wv4[q * 2];     wvb = wv4[q * 2 + 1];
        wvc = wv4[8 + q * 2]; wvd = wv4[8 + q * 2 + 1];
    }

    if (tid < 128) {                       // a0 rows + c0 for both owned columns
        int col = tid >> 6, o = tid & 63;
        int jc = col ? j1 : j0;
        p.aA[jc * 64 + o] = bj[col] * smwbi[o];            // h0 = 0
        smC[col][o] = bj[col] * smwbj[o] + smb1[o];
    }
    if (tid < 32) smH[tid >> 4][tid & 15] = 0.f;

    gbar(p.bar, 1);                        // a0 + Jt visible grid-wide

    // ---- load our two Jt rows, coalesced ----
    {
        const floatx4* Jt4 = (const floatx4*)p.Jt;
        int col = tid >> 7, t2 = tid & 127;
        int jc = col ? j1 : j0;
        ((floatx4*)&smJ[col][0])[t2] = Jt4[jc * 128 + t2];
    }
    __syncthreads();

    const float* aIn = p.aA;
    float* aOut = p.aB;

    for (int t = 0; t < NSTEPS; ++t) {
        const floatx4* c40 = (const floatx4*)&smC[0][0];
        const floatx4* c41 = (const floatx4*)&smC[1][0];
        floatx4 cva0 = c40[q*2], cvb0 = c40[q*2+1], cvc0 = c40[8+q*2], cvd0 = c40[8+q*2+1];
        floatx4 cva1 = c41[q*2], cvb1 = c41[q*2+1], cvc1 = c41[8+q*2], cvd1 = c41[8+q*2+1];

        floatx4 acc[2][4];
        #pragma unroll
        for (int col = 0; col < 2; ++col)
            #pragma unroll
            for (int nt = 0; nt < 4; ++nt) acc[col][nt] = (floatx4){0.f,0.f,0.f,0.f};

        const floatx4* a4 = (const floatx4*)aIn;

        for (int c8 = 0; c8 < 8; ++c8) {
            int i = w * 128 + c8 * 16 + m;
            float J0 = smJ[0][i], J1 = smJ[1][i];
            floatx4 av0 = a4[i*16 + q*2],     av1 = a4[i*16 + q*2 + 1];
            floatx4 av2 = a4[i*16 + 8 + q*2], av3 = a4[i*16 + 8 + q*2 + 1];

            floatx4 x0, x1, x2, x3;
            union { short8 s; unsigned u[4]; } fa0, fa1, fb0, fb1;
            #pragma unroll
            for (int e = 0; e < 4; ++e) {
                x0[e] = fmaxf(fmaf(J0, wva[e], av0[e]) + cva0[e], 0.f);
                x1[e] = fmaxf(fmaf(J0, wvb[e], av1[e]) + cvb0[e], 0.f);
                x2[e] = fmaxf(fmaf(J0, wvc[e], av2[e]) + cvc0[e], 0.f);
                x3[e] = fmaxf(fmaf(J0, wvd[e], av3[e]) + cvd0[e], 0.f);
            }
            fa0.u[0] = pk2bf(x0[0], x0[1]); fa0.u[1] = pk2bf(x0[2], x0[3]);
            fa0.u[2] = pk2bf(x1[0], x1[1]); fa0.u[3] = pk2bf(x1[2], x1[3]);
            fa1.u[0] = pk2bf(x2[0], x2[1]); fa1.u[1] = pk2bf(x2[2], x2[3]);
            fa1.u[2] = pk2bf(x3[0], x3[1]); fa1.u[3] = pk2bf(x3[2], x3[3]);
            #pragma unroll
            for (int e = 0; e < 4; ++e) {
                x0[e] = fmaxf(fmaf(J1, wva[e], av0[e]) + cva1[e], 0.f);
                x1[e] = fmaxf(fmaf(J1, wvb[e], av1[e]) + cvb1[e], 0.f);
                x2[e] = fmaxf(fmaf(J1, wvc[e], av2[e]) + cvc1[e], 0.f);
                x3[e] = fmaxf(fmaf(J1, wvd[e], av3[e]) + cvd1[e], 0.f);
            }
            fb0.u[0] = pk2bf(x0[0], x0[1]); fb0.u[1] = pk2bf(x0[2], x0[3]);
            fb0.u[2] = pk2bf(x1[0], x1[1]); fb0.u[3] = pk2bf(x1[2], x1[3]);
            fb1.u[0] = pk2bf(x2[0], x2[1]); fb1.u[1] = pk2bf(x2[2], x2[3]);
            fb1.u[2] = pk2bf(x3[0], x3[1]); fb1.u[3] = pk2bf(x3[2], x3[3]);

            #pragma unroll
            for (int nt = 0; nt < 4; ++nt) {
                floatx4 d = {0.f,0.f,0.f,0.f};
                d = __builtin_amdgcn_mfma_f32_16x16x32_bf16(fa0.s, bfw[nt][0], d, 0, 0, 0);
                d = __builtin_amdgcn_mfma_f32_16x16x32_bf16(fa1.s, bfw[nt][1], d, 0, 0, 0);
                floatx4 d2 = {0.f,0.f,0.f,0.f};
                d2 = __builtin_amdgcn_mfma_f32_16x16x32_bf16(fb0.s, bfw[nt][0], d2, 0, 0, 0);
                d2 = __builtin_amdgcn_mfma_f32_16x16x32_bf16(fb1.s, bfw[nt][1], d2, 0, 0, 0);
                #pragma unroll
                for (int r = 0; r < 4; ++r) {
                    acc[0][nt][r] += fmaxf(d[r]  + b2n[nt], 0.f);
                    acc[1][nt][r] += fmaxf(d2[r] + b2n[nt], 0.f);
                }
            }
        }

        // per-col reduction over i
        #pragma unroll
        for (int col = 0; col < 2; ++col)
            #pragma unroll
            for (int nt = 0; nt < 4; ++nt) {
                float v = acc[col][nt][0] + acc[col][nt][1] + acc[col][nt][2] + acc[col][nt][3];
                v += __shfl_xor(v, 16);
                v += __shfl_xor(v, 32);
                if (l < 16) smWave[col][w][nt*16 + l] = v;
            }
        if (tid < 32) smGin[tid >> 4][tid & 15] = smH[tid >> 4][tid & 15];
        __syncthreads();
        if (tid < 128) {
            int col = tid >> 6, o = tid & 63;
            smMacc[col][o] = smWave[col][0][o] + smWave[col][1][o]
                           + smWave[col][2][o] + smWave[col][3][o];
        }
        __syncthreads();

        // msg = W3 @ macc + 512*b3 (per col: 32 outs x 4 partials)
        {
            int col = tid >> 7, t2 = tid & 127;
            int o = t2 >> 2, pp = t2 & 3;
            const floatx4* W3v = (const floatx4*)p.W3;
            floatx4 w0 = W3v[o*16 + pp*4],     w1 = W3v[o*16 + pp*4 + 1];
            floatx4 w2 = W3v[o*16 + pp*4 + 2], w3 = W3v[o*16 + pp*4 + 3];
            float part = 0.f;
            #pragma unroll
            for (int e = 0; e < 4; ++e) {
                part = fmaf(w0[e], smMacc[col][pp*16 + e],      part);
                part = fmaf(w1[e], smMacc[col][pp*16 + 4 + e],  part);
                part = fmaf(w2[e], smMacc[col][pp*16 + 8 + e],  part);
                part = fmaf(w3[e], smMacc[col][pp*16 + 12 + e], part);
            }
            part += __shfl_xor(part, 1);
            part += __shfl_xor(part, 2);
            if (pp == 0) smGin[col][16 + o] = part + 512.f * p.b3[o];
        }
        __syncthreads();

        // GRU gates: per col, t2<48 -> gi (serial 48-dot), t2 in [64,112) -> gh
        {
            int col = tid >> 7, t2 = tid & 127;
            if (t2 < 48) {
                const floatx4* Wv = (const floatx4*)p.W_ih;
                const floatx4* g4 = (const floatx4*)&smGin[col][0];
                float s = p.b_ih[t2];
                #pragma unroll
                for (int e = 0; e < 12; ++e) {
                    floatx4 we = Wv[t2*12 + e], ge = g4[e];
                    s = fmaf(we[0], ge[0], s); s = fmaf(we[1], ge[1], s);
                    s = fmaf(we[2], ge[2], s); s = fmaf(we[3], ge[3], s);
                }
                smGi[col][t2] = s;
            } else if (t2 >= 64 && t2 < 112) {
                int o = t2 - 64;
                const floatx4* Wv = (const floatx4*)p.W_hh;
                const floatx4* h4 = (const floatx4*)&smGin[col][0];  // old h
                float s = p.b_hh[o];
                #pragma unroll
                for (int e = 0; e < 4; ++e) {
                    floatx4 we = Wv[o*4 + e], he = h4[e];
                    s = fmaf(we[0], he[0], s); s = fmaf(we[1], he[1], s);
                    s = fmaf(we[2], he[2], s); s = fmaf(we[3], he[3], s);
                }
                smGh[col][o] = s;
            }
        }
        __syncthreads();

        if (tid < 32) {
            int col = tid >> 4, o = tid & 15;
            float r = 1.f / (1.f + __expf(-(smGi[col][o] + smGh[col][o])));
            float z = 1.f / (1.f + __expf(-(smGi[col][16+o] + smGh[col][16+o])));
            float n = tanhf(smGi[col][32+o] + r * smGh[col][32+o]);
            smH[col][o] = (1.f - z) * n + z * smGin[col][o];
        }
        __syncthreads();

        if (t < NSTEPS - 1) {
            // next projections: per col 128 threads (64 a -> global, 64 c -> LDS)
            {
                int col = tid >> 7, t2 = tid & 127, o = t2 & 63, sel = t2 >> 6;
                const floatx4* Wv = (const floatx4*)(sel ? &smW1hj[0][0] : &smW1hi[0][0]);
                const floatx4* h4 = (const floatx4*)&smH[col][0];
                floatx4 w0 = Wv[o*4], w1 = Wv[o*4+1], w2 = Wv[o*4+2], w3 = Wv[o*4+3];
                float s = 0.f;
                #pragma unroll
                for (int e = 0; e < 4; ++e) {
                    s = fmaf(w0[e], h4[0][e], s);
                    s = fmaf(w1[e], h4[1][e], s);
                    s = fmaf(w2[e], h4[2][e], s);
                    s = fmaf(w3[e], h4[3][e], s);
                }
                int jc = col ? j1 : j0;
                if (sel == 0) aOut[jc*64 + o] = s + bj[col] * smwbi[o];
                else          smC[col][o]     = s + bj[col] * smwbj[o] + smb1[o];
            }
            gbar(p.bar, (unsigned)(t + 2));
            const float* tmp = aIn; aIn = aOut; aOut = (float*)tmp;
        }
    }

    // ---- fused readout for both owned nodes ----
    {
        int col = tid >> 7, t2 = tid & 127;
        if (t2 < 64) {
            const floatx4* Wv = (const floatx4*)p.Wr1;
            const floatx4* h4 = (const floatx4*)&smH[col][0];
            floatx4 w0 = Wv[t2*4], w1 = Wv[t2*4+1], w2 = Wv[t2*4+2], w3 = Wv[t2*4+3];
            float s = p.br1[t2];
            #pragma unroll
            for (int e = 0; e < 4; ++e) {
                s = fmaf(w0[e], h4[0][e], s);
                s = fmaf(w1[e], h4[1][e], s);
                s = fmaf(w2[e], h4[2][e], s);
                s = fmaf(w3[e], h4[3][e], s);
            }
            smY[col][t2] = fmaxf(s, 0.f);
        }
    }
    __syncthreads();
    {
        int col = tid >> 7, t2 = tid & 127;
        int o = t2 >> 1, pp = t2 & 1;
        const floatx4* Wv = (const floatx4*)p.Wr2;
        const floatx4* y4 = (const floatx4*)&smY[col][0];
        float part = 0.f;
        #pragma unroll
        for (int e = 0; e < 8; ++e) {
            floatx4 we = Wv[o*16 + pp*8 + e], ye = y4[pp*8 + e];
            part = fmaf(we[0], ye[0], part); part = fmaf(we[1], ye[1], part);
            part = fmaf(we[2], ye[2], part); part = fmaf(we[3], ye[3], part);
        }
        part += __shfl_xor(part, 1);
        if (pp == 0) smY2[col][o] = fmaxf(part + p.br2[o], 0.f);
    }
    __syncthreads();
    {
        int col = tid >> 7, t2 = tid & 127;
        int ot = t2 >> 6, pp = t2 & 63;
        float part = p.Wr3[ot*64 + pp] * smY2[col][pp];
        part += __shfl_xor(part, 1);
        part += __shfl_xor(part, 2);
        part += __shfl_xor(part, 4);
        part += __shfl_xor(part, 8);
        part += __shfl_xor(part, 16);
        part += __shfl_xor(part, 32);
        if (pp == 0) smR[col][ot] = part + p.br3[ot];
    }
    __syncthreads();
    if (tid < 2) {
        int col = tid;
        int jc = col ? j1 : j0;
        float e0 = 1.f / (1.f + __expf(-smR[col][0]));
        float e1 = 1.f / (1.f + __expf(-smR[col][1]));
        float tsum = e0 + e1;
        p.out[jc*2]     = e0 / tsum;
        p.out[jc*2 + 1] = e1 / tsum;
    }
}

extern "C" void kernel_launch(void* const* d_in, const int* in_sizes, int n_in,
                              void* d_out, int out_size, void* d_ws, size_t ws_size,
                              hipStream_t stream)
{
    Params par;
    par.J    = (const float*)d_in[0];
    par.b    = (const float*)d_in[1];
    par.W1   = (const float*)d_in[2];
    par.b1   = (const float*)d_in[3];
    par.W2   = (const float*)d_in[4];
    par.b2   = (const float*)d_in[5];
    par.W3   = (const float*)d_in[6];
    par.b3   = (const float*)d_in[7];
    par.W_ih = (const float*)d_in[8];
    par.b_ih = (const float*)d_in[9];
    par.W_hh = (const float*)d_in[10];
    par.b_hh = (const float*)d_in[11];
    par.Wr1  = (const float*)d_in[12];
    par.br1  = (const float*)d_in[13];
    par.Wr2  = (const float*)d_in[14];
    par.br2  = (const float*)d_in[15];
    par.Wr3  = (const float*)d_in[16];
    par.br3  = (const float*)d_in[17];
    par.out  = (float*)d_out;

    float* ws = (float*)d_ws;
    par.aA  = ws;                               // 512*64
    par.aB  = ws + 32768;                       // 512*64
    par.Jt  = ws + 65536;                       // 512*512
    par.bar = (unsigned*)(ws + 65536 + 262144); // barrier lines

    hipMemsetAsync(par.bar, 0, 1024, stream);   // zero barrier state (ws poisoned 0xAA)
    hipLaunchKernelGGL(ggnn_fused, dim3(256), dim3(256), 0, stream, par);
}

// Round 6
// 163.839 us; speedup vs baseline: 2.2102x; 1.8353x over previous
//
#include <hip/hip_runtime.h>
#include <hip/hip_bf16.h>

#define NSTEPS 5
#define ABUFSZ 32768   // 512*64 floats per step buffer

typedef __attribute__((ext_vector_type(8))) short short8;
typedef __attribute__((ext_vector_type(4))) float floatx4;

static __device__ __forceinline__ unsigned pk2bf(float a, float b) {
    __hip_bfloat162 h = __float22bfloat162_rn(make_float2(a, b));
    return *reinterpret_cast<unsigned*>(&h);
}

// write-through stores: data visible at device coherence point (no fence needed)
static __device__ __forceinline__ void store_wt4(float* addr, floatx4 v) {
    __asm__ volatile("global_store_dwordx4 %0, %1, off sc0 sc1"
                     :: "v"(addr), "v"(v) : "memory");
}
static __device__ __forceinline__ void store_wt1(float* addr, float v) {
    __asm__ volatile("global_store_dword %0, %1, off sc0 sc1"
                     :: "v"(addr), "v"(v) : "memory");
}

struct Params {
    const float *J, *b, *W1, *b1, *W2, *b2, *W3, *b3;
    const float *W_ih, *b_ih, *W_hh, *b_hh;
    const float *Wr1, *br1, *Wr2, *br2, *Wr3, *br3;
    float *out;
    float *aBase;          // NSTEPS rotating a-buffers (512x64 each)
    float *Jt;             // transposed J (512x512)
    unsigned *bar;         // tree barrier state (monotonic counters)
};

// Monotonic tree grid barrier, 512 blocks, all-RELAXED atomics (no L2
// invalidates). Producer visibility comes from write-through stores +
// the vmcnt(0) below. bar[g*16] g=0..7 group ctrs (64 blocks each),
// bar[128] master, bar[144] generation. Counters never reset.
static __device__ __forceinline__ void gbar(unsigned* bar, unsigned ph) {
    __builtin_amdgcn_s_waitcnt(0);         // this wave's WT stores reached coherence pt
    __syncthreads();                       // => all waves' stores done
    if (threadIdx.x == 0) {
        const int g = blockIdx.x & 7;
        unsigned old = __hip_atomic_fetch_add(&bar[g * 16], 1u, __ATOMIC_RELAXED,
                                              __HIP_MEMORY_SCOPE_AGENT);
        if (old == 64u * ph - 1u) {
            unsigned mo = __hip_atomic_fetch_add(&bar[128], 1u, __ATOMIC_RELAXED,
                                                 __HIP_MEMORY_SCOPE_AGENT);
            if (mo == 8u * ph - 1u)
                __hip_atomic_store(&bar[144], ph, __ATOMIC_RELAXED,
                                   __HIP_MEMORY_SCOPE_AGENT);
        }
        while (__hip_atomic_load(&bar[144], __ATOMIC_RELAXED,
                                 __HIP_MEMORY_SCOPE_AGENT) < ph)
            __builtin_amdgcn_s_sleep(2);
    }
    __syncthreads();
    __asm__ volatile("" ::: "memory");     // keep compiler from hoisting loads above
}

__global__ __launch_bounds__(256, 2) void ggnn_fused(Params p)
{
    const int tid = threadIdx.x;
    const int l = tid & 63, w = tid >> 6;
    const int m = l & 15, q = l >> 4;
    const int j = blockIdx.x;

    __shared__ __align__(16) float smTile[64][65];   // transpose staging (init only)
    __shared__ __align__(16) float smJ[512];         // column j of J
    __shared__ __align__(16) float smW1hi[64][16];
    __shared__ __align__(16) float smW1hj[64][16];
    __shared__ __align__(16) float smwJ[64], smwbi[64], smwbj[64], smb1[64];
    __shared__ __align__(16) float smC[64];
    __shared__ __align__(16) float smA[64];
    __shared__ __align__(16) float smH[16];
    __shared__ __align__(16) float smWave[4][64];
    __shared__ __align__(16) float smMacc[64];
    __shared__ __align__(16) float smGin[48];        // [h(16), msg(32)]
    __shared__ __align__(16) float smGi[48], smGh[48];
    __shared__ __align__(16) float smY[64], smY2[64];
    __shared__ float smR[2];

    // ---- init phase: blocks 0..63 transpose J into Jt (write-through) ----
    if (blockIdx.x < 64) {
        int ti = blockIdx.x >> 3, tj = blockIdx.x & 7;
        for (int pp = 0; pp < 16; ++pp) {
            int e = pp * 256 + tid; int r = e >> 6, c = e & 63;
            smTile[r][c] = p.J[(ti * 64 + r) * 512 + tj * 64 + c];
        }
        __syncthreads();
        for (int pp = 0; pp < 16; ++pp) {
            int e = pp * 256 + tid; int r = e >> 6, c = e & 63;
            store_wt1(p.Jt + (tj * 64 + r) * 512 + ti * 64 + c, smTile[c][r]);
        }
    }

    // ---- stage weights, pack W2 frags ----
    if (tid < 64) {
        int o = tid;
        #pragma unroll
        for (int s = 0; s < 16; ++s) {
            smW1hi[o][s] = p.W1[o * 35 + s];
            smW1hj[o][s] = p.W1[o * 35 + 16 + s];
        }
        smwJ[o]  = p.W1[o * 35 + 32];
        smwbi[o] = p.W1[o * 35 + 33];
        smwbj[o] = p.W1[o * 35 + 34];
        smb1[o]  = p.b1[o];
    }

    short8 bfw[4][2];
    float b2n[4];
    {
        const floatx4* W2v = (const floatx4*)p.W2;
        #pragma unroll
        for (int nt = 0; nt < 4; ++nt) {
            int n = nt * 16 + m;
            #pragma unroll
            for (int ks = 0; ks < 2; ++ks) {
                int kb = ks * 32 + q * 8;
                floatx4 f0 = W2v[n * 16 + (kb >> 2)];
                floatx4 f1 = W2v[n * 16 + (kb >> 2) + 1];
                union { short8 s; unsigned u[4]; } t;
                t.u[0] = pk2bf(f0[0], f0[1]); t.u[1] = pk2bf(f0[2], f0[3]);
                t.u[2] = pk2bf(f1[0], f1[1]); t.u[3] = pk2bf(f1[2], f1[3]);
                bfw[nt][ks] = t.s;
            }
            b2n[nt] = p.b2[nt * 16 + m];
        }
    }
    __syncthreads();

    const float bj = p.b[j];

    floatx4 wva, wvb, wvc, wvd;
    {
        const floatx4* wv4 = (const floatx4*)smwJ;
        wva = wv4[q * 2];     wvb = wv4[q * 2 + 1];
        wvc = wv4[8 + q * 2]; wvd = wv4[8 + q * 2 + 1];
    }

    if (tid < 64) smC[tid] = bj * smwbj[tid] + smb1[tid];   // c0_j
    if (tid < 16) {                                          // a0 row j (h0=0), WT
        floatx4 v;
        #pragma unroll
        for (int e = 0; e < 4; ++e) v[e] = bj * smwbi[tid * 4 + e];
        store_wt4(p.aBase + j * 64 + tid * 4, v);
        smH[tid] = 0.f;
    }

    gbar(p.bar, 1);                        // a0 + Jt at coherence point, grid synced

    // ---- load our Jt row once (read-once lines -> cached loads safe) ----
    if (tid < 128) ((floatx4*)smJ)[tid] = ((const floatx4*)p.Jt)[j * 128 + tid];
    __syncthreads();

    for (int t = 0; t < NSTEPS; ++t) {
        const float* aIn = p.aBase + t * ABUFSZ;
        const floatx4* c4 = (const floatx4*)smC;
        floatx4 cva = c4[q*2], cvb = c4[q*2+1], cvc = c4[8+q*2], cvd = c4[8+q*2+1];

        floatx4 acc[4];
        #pragma unroll
        for (int nt = 0; nt < 4; ++nt) acc[nt] = (floatx4){0.f,0.f,0.f,0.f};

        const floatx4* a4 = (const floatx4*)aIn;

        for (int c8 = 0; c8 < 8; ++c8) {
            int i = w * 128 + c8 * 16 + m;
            float Jij = smJ[i];
            floatx4 av0 = a4[i*16 + q*2],     av1 = a4[i*16 + q*2 + 1];
            floatx4 av2 = a4[i*16 + 8 + q*2], av3 = a4[i*16 + 8 + q*2 + 1];
            floatx4 x0, x1, x2, x3;
            #pragma unroll
            for (int e = 0; e < 4; ++e) {
                x0[e] = fmaxf(fmaf(Jij, wva[e], av0[e]) + cva[e], 0.f);
                x1[e] = fmaxf(fmaf(Jij, wvb[e], av1[e]) + cvb[e], 0.f);
                x2[e] = fmaxf(fmaf(Jij, wvc[e], av2[e]) + cvc[e], 0.f);
                x3[e] = fmaxf(fmaf(Jij, wvd[e], av3[e]) + cvd[e], 0.f);
            }
            union { short8 s; unsigned u[4]; } fa0, fa1;
            fa0.u[0] = pk2bf(x0[0], x0[1]); fa0.u[1] = pk2bf(x0[2], x0[3]);
            fa0.u[2] = pk2bf(x1[0], x1[1]); fa0.u[3] = pk2bf(x1[2], x1[3]);
            fa1.u[0] = pk2bf(x2[0], x2[1]); fa1.u[1] = pk2bf(x2[2], x2[3]);
            fa1.u[2] = pk2bf(x3[0], x3[1]); fa1.u[3] = pk2bf(x3[2], x3[3]);
            #pragma unroll
            for (int nt = 0; nt < 4; ++nt) {
                floatx4 d = {0.f,0.f,0.f,0.f};
                d = __builtin_amdgcn_mfma_f32_16x16x32_bf16(fa0.s, bfw[nt][0], d, 0, 0, 0);
                d = __builtin_amdgcn_mfma_f32_16x16x32_bf16(fa1.s, bfw[nt][1], d, 0, 0, 0);
                #pragma unroll
                for (int r = 0; r < 4; ++r)
                    acc[nt][r] += fmaxf(d[r] + b2n[nt], 0.f);
            }
        }

        // reduce rows within wave; stage old h
        #pragma unroll
        for (int nt = 0; nt < 4; ++nt) {
            float v = acc[nt][0] + acc[nt][1] + acc[nt][2] + acc[nt][3];
            v += __shfl_xor(v, 16);
            v += __shfl_xor(v, 32);
            if (l < 16) smWave[w][nt*16 + l] = v;
        }
        if (tid < 16) smGin[tid] = smH[tid];
        __syncthreads();
        if (tid < 64) smMacc[tid] = smWave[0][tid] + smWave[1][tid]
                                  + smWave[2][tid] + smWave[3][tid];
        __syncthreads();

        // msg = W3 @ macc + 512*b3
        {
            int o = tid >> 3, pp = tid & 7;
            const floatx4* W3v = (const floatx4*)p.W3;
            floatx4 wv0 = W3v[o*16 + pp*2], wv1 = W3v[o*16 + pp*2 + 1];
            float part = 0.f;
            #pragma unroll
            for (int e = 0; e < 4; ++e) {
                part = fmaf(wv0[e], smMacc[pp*8 + e], part);
                part = fmaf(wv1[e], smMacc[pp*8 + 4 + e], part);
            }
            part += __shfl_xor(part, 1);
            part += __shfl_xor(part, 2);
            part += __shfl_xor(part, 4);
            if (pp == 0) smGin[16 + o] = part + 512.f * p.b3[o];
        }
        __syncthreads();

        // GRU gates
        if (tid < 192) {
            int o = tid >> 2, pp = tid & 3;
            const floatx4* Wv = (const floatx4*)p.W_ih;
            floatx4 w0 = Wv[o*12 + pp*3], w1 = Wv[o*12 + pp*3 + 1], w2 = Wv[o*12 + pp*3 + 2];
            int k0 = pp * 12;
            float part = 0.f;
            #pragma unroll
            for (int e = 0; e < 4; ++e) {
                part = fmaf(w0[e], smGin[k0 + e], part);
                part = fmaf(w1[e], smGin[k0 + 4 + e], part);
                part = fmaf(w2[e], smGin[k0 + 8 + e], part);
            }
            part += __shfl_xor(part, 1);
            part += __shfl_xor(part, 2);
            if (pp == 0) smGi[o] = part + p.b_ih[o];
        } else if (tid < 240) {
            int o = tid - 192;
            const floatx4* Wv = (const floatx4*)p.W_hh;
            floatx4 w0 = Wv[o*4], w1 = Wv[o*4+1], w2 = Wv[o*4+2], w3 = Wv[o*4+3];
            float s = p.b_hh[o];
            #pragma unroll
            for (int e = 0; e < 4; ++e) {
                s = fmaf(w0[e], smGin[e],      s);
                s = fmaf(w1[e], smGin[4 + e],  s);
                s = fmaf(w2[e], smGin[8 + e],  s);
                s = fmaf(w3[e], smGin[12 + e], s);
            }
            smGh[o] = s;
        }
        __syncthreads();

        if (tid < 16) {
            float r = 1.f / (1.f + __expf(-(smGi[tid] + smGh[tid])));
            float z = 1.f / (1.f + __expf(-(smGi[16+tid] + smGh[16+tid])));
            float n = tanhf(smGi[32+tid] + r * smGh[32+tid]);
            smH[tid] = (1.f - z) * n + z * smGin[tid];
        }
        __syncthreads();

        if (t < NSTEPS - 1) {
            // next projections: 0..63 -> smA, 64..127 -> smC
            if (tid < 128) {
                int o = tid & 63, sel = tid >> 6;
                const floatx4* Wv = (const floatx4*)(sel ? &smW1hj[0][0] : &smW1hi[0][0]);
                const floatx4* h4 = (const floatx4*)smH;
                floatx4 w0 = Wv[o*4], w1 = Wv[o*4+1], w2 = Wv[o*4+2], w3 = Wv[o*4+3];
                float s = 0.f;
                #pragma unroll
                for (int e = 0; e < 4; ++e) {
                    s = fmaf(w0[e], h4[0][e], s);
                    s = fmaf(w1[e], h4[1][e], s);
                    s = fmaf(w2[e], h4[2][e], s);
                    s = fmaf(w3[e], h4[3][e], s);
                }
                if (sel == 0) smA[o] = s + bj * smwbi[o];
                else          smC[o] = s + bj * smwbj[o] + smb1[o];
            }
            __syncthreads();
            if (tid < 16) {     // write-through a row j into next rotation buffer
                float* aNext = p.aBase + (t + 1) * ABUFSZ;
                store_wt4(aNext + j * 64 + tid * 4, ((floatx4*)smA)[tid]);
            }
            gbar(p.bar, (unsigned)(t + 2));
        }
    }

    // ---- fused readout for node j ----
    if (tid < 64) {
        const floatx4* Wv = (const floatx4*)p.Wr1;
        const floatx4* h4 = (const floatx4*)smH;
        floatx4 w0 = Wv[tid*4], w1 = Wv[tid*4+1], w2 = Wv[tid*4+2], w3 = Wv[tid*4+3];
        float s = p.br1[tid];
        #pragma unroll
        for (int e = 0; e < 4; ++e) {
            s = fmaf(w0[e], h4[0][e], s);
            s = fmaf(w1[e], h4[1][e], s);
            s = fmaf(w2[e], h4[2][e], s);
            s = fmaf(w3[e], h4[3][e], s);
        }
        smY[tid] = fmaxf(s, 0.f);
    }
    __syncthreads();
    {
        int o = tid >> 2, pp = tid & 3;
        const floatx4* Wv = (const floatx4*)p.Wr2;
        const floatx4* y4 = (const floatx4*)smY;
        floatx4 w0 = Wv[o*16 + pp*4],     w1 = Wv[o*16 + pp*4 + 1];
        floatx4 w2 = Wv[o*16 + pp*4 + 2], w3 = Wv[o*16 + pp*4 + 3];
        float part = 0.f;
        #pragma unroll
        for (int e = 0; e < 4; ++e) {
            part = fmaf(w0[e], y4[pp*4][e] * 0.f + smY[pp*16 + e],      part);
            part = fmaf(w1[e], smY[pp*16 + 4 + e],  part);
            part = fmaf(w2[e], smY[pp*16 + 8 + e],  part);
            part = fmaf(w3[e], smY[pp*16 + 12 + e], part);
        }
        part += __shfl_xor(part, 1);
        part += __shfl_xor(part, 2);
        if (pp == 0) smY2[o] = fmaxf(part + p.br2[o], 0.f);
    }
    __syncthreads();
    if (tid < 128) {
        int ot = tid >> 6, pp = tid & 63;
        float part = p.Wr3[ot*64 + pp] * smY2[pp];
        part += __shfl_xor(part, 1);
        part += __shfl_xor(part, 2);
        part += __shfl_xor(part, 4);
        part += __shfl_xor(part, 8);
        part += __shfl_xor(part, 16);
        part += __shfl_xor(part, 32);
        if (pp == 0) smR[ot] = part + p.br3[ot];
    }
    __syncthreads();
    if (tid == 0) {
        float e0 = 1.f / (1.f + __expf(-smR[0]));
        float e1 = 1.f / (1.f + __expf(-smR[1]));
        float tsum = e0 + e1;
        p.out[j*2]     = e0 / tsum;
        p.out[j*2 + 1] = e1 / tsum;
    }
}

extern "C" void kernel_launch(void* const* d_in, const int* in_sizes, int n_in,
                              void* d_out, int out_size, void* d_ws, size_t ws_size,
                              hipStream_t stream)
{
    Params par;
    par.J    = (const float*)d_in[0];
    par.b    = (const float*)d_in[1];
    par.W1   = (const float*)d_in[2];
    par.b1   = (const float*)d_in[3];
    par.W2   = (const float*)d_in[4];
    par.b2   = (const float*)d_in[5];
    par.W3   = (const float*)d_in[6];
    par.b3   = (const float*)d_in[7];
    par.W_ih = (const float*)d_in[8];
    par.b_ih = (const float*)d_in[9];
    par.W_hh = (const float*)d_in[10];
    par.b_hh = (const float*)d_in[11];
    par.Wr1  = (const float*)d_in[12];
    par.br1  = (const float*)d_in[13];
    par.Wr2  = (const float*)d_in[14];
    par.br2  = (const float*)d_in[15];
    par.Wr3  = (const float*)d_in[16];
    par.br3  = (const float*)d_in[17];
    par.out  = (float*)d_out;

    float* ws = (float*)d_ws;
    par.aBase = ws;                                   // 5 x 32768 floats
    par.Jt    = ws + NSTEPS * ABUFSZ;                 // 512*512
    par.bar   = (unsigned*)(ws + NSTEPS * ABUFSZ + 262144);

    hipMemsetAsync(par.bar, 0, 1024, stream);         // zero barrier state
    hipLaunchKernelGGL(ggnn_fused, dim3(512), dim3(256), 0, stream, par);
}